// Round 6
// baseline (288.540 us; speedup 1.0000x reference)
//
#include <hip/hip_runtime.h>

#define N_NODES 100000
#define NF      128
#define NE      600000
#define NG      1000
#define EPSF    1e-5f

#define STATS_NB (N_NODES / 32)              // 3125 blocks, 4 waves x 8 rows
#define DEG_NB   (((NE / 4) + 255) / 256)    // 586 blocks, int4 edges
#define ALLOC_NB ((N_NODES + 255) / 256)     // 391
#define BRED_NB  64
#define PREP_NB  ((NG * NF) / 256 + 1)       // 501

// ================= K1: per-graph stats ∥ degree count =================
__global__ __launch_bounds__(256) void k1_stats_deg(
    const float* __restrict__ x, const int* __restrict__ gid,
    const int* __restrict__ edst,
    float* __restrict__ gsum, float* __restrict__ gsq, int* __restrict__ cnt,
    int* __restrict__ deg)
{
    if (blockIdx.x >= STATS_NB) {
        int t = (blockIdx.x - STATS_NB) * 256 + threadIdx.x;
        if (t < NE / 4) {
            const int4 d4 = reinterpret_cast<const int4*>(edst)[t];
            atomicAdd(&deg[d4.x], 1);
            atomicAdd(&deg[d4.y], 1);
            atomicAdd(&deg[d4.z], 1);
            atomicAdd(&deg[d4.w], 1);
        }
        return;
    }
    // wave owns 8 contiguous rows; graph_id sorted -> run-flush
    const int wave = threadIdx.x >> 6;
    const int lane = threadIdx.x & 63;
    const int f = lane * 2;
    const int r0 = blockIdx.x * 32 + wave * 8;
    const int r1 = r0 + 8;

    float gsx = 0.f, gsy = 0.f, gqx = 0.f, gqy = 0.f;
    int cur = gid[r0];
    int runStart = r0;

    for (int r = r0; r < r1; ++r) {
        int g = gid[r];                  // wave-uniform
        if (g != cur) {
            atomicAdd(&gsum[cur * NF + f],     gsx);
            atomicAdd(&gsum[cur * NF + f + 1], gsy);
            atomicAdd(&gsq [cur * NF + f],     gqx);
            atomicAdd(&gsq [cur * NF + f + 1], gqy);
            if (lane == 0) atomicAdd(&cnt[cur], r - runStart);
            gsx = gsy = gqx = gqy = 0.f;
            cur = g; runStart = r;
        }
        const float2 v = *reinterpret_cast<const float2*>(x + (size_t)r * NF + f);
        gsx += v.x; gsy += v.y; gqx += v.x * v.x; gqy += v.y * v.y;
    }
    atomicAdd(&gsum[cur * NF + f],     gsx);
    atomicAdd(&gsum[cur * NF + f + 1], gsy);
    atomicAdd(&gsq [cur * NF + f],     gqx);
    atomicAdd(&gsq [cur * NF + f + 1], gqy);
    if (lane == 0) atomicAdd(&cnt[cur], r1 - runStart);
}

// ================= K2: segment alloc (no scan) ∥ batch reduction =================
__global__ __launch_bounds__(256) void k2_alloc_bred(
    const int* __restrict__ deg, int2* __restrict__ odeg, int* __restrict__ cursor,
    int* __restrict__ total,
    const float* __restrict__ gsum, const float* __restrict__ gsq,
    float* __restrict__ bsum, float* __restrict__ bsq)
{
    if (blockIdx.x < ALLOC_NB) {
        const int i = blockIdx.x * 256 + threadIdx.x;
        const int lane = threadIdx.x & 63;
        int d = (i < N_NODES) ? deg[i] : 0;
        int p = d;                           // inclusive wave prefix sum
#pragma unroll
        for (int st = 1; st < 64; st <<= 1) {
            int v = __shfl_up(p, st, 64);
            if (lane >= st) p += v;
        }
        int wtot = __shfl(p, 63, 64);
        int base = 0;
        if (lane == 63) base = atomicAdd(total, wtot);
        base = __shfl(base, 63, 64);
        if (i < N_NODES) {
            int o = base + p - d;            // exclusive start of my segment
            odeg[i] = make_int2(o, d);
            cursor[i] = o;
        }
    } else {
        // bsum[f] = sum_g gsum[g][f]
        int b = blockIdx.x - ALLOC_NB;
        int t = threadIdx.x;
        int f = t & 127, gl = t >> 7;
        float s = 0.f, q = 0.f;
#pragma unroll
        for (int k = 0; k < 8; ++k) {
            int g = b * 16 + gl * 8 + k;
            if (g < NG) { s += gsum[g * NF + f]; q += gsq[g * NF + f]; }
        }
        atomicAdd(&bsum[f], s);
        atomicAdd(&bsq[f], q);
    }
}

// ================= K3: CSR fill ∥ prep (tables -> mu/rstd, feature constants) =================
// fc[f*8] = { mb, rvb, w0*g/s, w1*g/s, w2*g/s, w3*g/s, beta, 0 }
__global__ __launch_bounds__(256) void k3_fill_prep(
    const int* __restrict__ esrc, const int* __restrict__ edst,
    int* __restrict__ cursor, int* __restrict__ nbr,
    float* __restrict__ gsum, float* __restrict__ gsq, const int* __restrict__ cnt,
    const float* __restrict__ bsum, const float* __restrict__ bsq,
    const float* __restrict__ gamma, const float* __restrict__ beta,
    const float* __restrict__ lb, const float* __restrict__ lg,
    const float* __restrict__ la, const float* __restrict__ ln,
    float* __restrict__ fc)
{
    if (blockIdx.x < DEG_NB) {
        int t = blockIdx.x * 256 + threadIdx.x;
        if (t < NE / 4) {
            const int4 d4 = reinterpret_cast<const int4*>(edst)[t];
            const int4 s4 = reinterpret_cast<const int4*>(esrc)[t];
            int p;
            p = atomicAdd(&cursor[d4.x], 1); nbr[p] = s4.x;
            p = atomicAdd(&cursor[d4.y], 1); nbr[p] = s4.y;
            p = atomicAdd(&cursor[d4.z], 1); nbr[p] = s4.z;
            p = atomicAdd(&cursor[d4.w], 1); nbr[p] = s4.w;
        }
        return;
    }
    int b = blockIdx.x - DEG_NB;
    if (b < (NG * NF) / 256) {               // 500 blocks: elementwise convert
        int idx = b * 256 + threadIdx.x;
        int g = idx >> 7;
        float c = (float)cnt[g]; if (c < 1.f) c = 1.f;
        float rc = 1.0f / c;
        float m = gsum[idx] * rc;
        float v = gsq[idx] * rc - m * m; if (v < 0.f) v = 0.f;
        gsum[idx] = m;
        gsq[idx]  = rsqrtf(v + EPSF);
    } else if (threadIdx.x < NF) {           // last block: per-feature constants
        int f = threadIdx.x;
        float mb = bsum[f] * (1.0f / N_NODES);
        float vb = bsq[f] * (1.0f / N_NODES) - mb * mb;   // no clamp: matches reference
        float rvb = rsqrtf(vb + EPSF);
        float l0 = lb[f], l1 = lg[f], l2 = la[f], l3 = ln[f];
        float m = fmaxf(fmaxf(l0, l1), fmaxf(l2, l3));
        float w0 = __expf(l0 - m), w1 = __expf(l1 - m), w2 = __expf(l2 - m), w3 = __expf(l3 - m);
        float rs = gamma[f] / (w0 + w1 + w2 + w3);
        float* p = fc + f * 8;
        p[0] = mb; p[1] = rvb;
        p[2] = w0 * rs; p[3] = w1 * rs; p[4] = w2 * rs; p[5] = w3 * rs;
        p[6] = beta[f]; p[7] = 0.f;
    }
}

// ================= K5: fused final, 2 nodes per wave for gather MLP =================
__global__ __launch_bounds__(256) void k5_final(
    const float* __restrict__ x, const int* __restrict__ gid,
    const float* __restrict__ gmu, const float* __restrict__ grs,
    const float* __restrict__ fc, const int2* __restrict__ odeg,
    const int* __restrict__ nbr, float* __restrict__ out)
{
    const int wave = threadIdx.x >> 6;
    const int lane = threadIdx.x & 63;
    const int i0 = blockIdx.x * 8 + wave * 2;
    const int i1 = i0 + 1;
    const int f = lane * 2;

    const float2 xa = *reinterpret_cast<const float2*>(x + (size_t)i0 * NF + f);
    const float2 xb = *reinterpret_cast<const float2*>(x + (size_t)i1 * NF + f);

    // per-feature constants: {mb, rvb, w0, w1} {w2, w3, beta, pad}
    const float4 c0 = *reinterpret_cast<const float4*>(fc + f * 8);
    const float4 c1 = *reinterpret_cast<const float4*>(fc + f * 8 + 4);
    const float4 d0 = *reinterpret_cast<const float4*>(fc + (f + 1) * 8);
    const float4 d1 = *reinterpret_cast<const float4*>(fc + (f + 1) * 8 + 4);

    // ---- adjacency gather: interleaved dual-node, predicated 8-deep batches ----
    const int2 oa = odeg[i0], ob = odeg[i1];
    const int sa = oa.x, da = oa.y, sb = ob.x, db = ob.y;
    float asx = 0.f, asy = 0.f, aqx = 0.f, aqy = 0.f;
    float bsx = 0.f, bsy = 0.f, bqx = 0.f, bqy = 0.f;
    int ka = 0, kb = 0;
    while (ka < da || kb < db) {
        int ia_[8], ib_[8];
        const bool hA = ka < da, hB = kb < db;   // wave-uniform
        if (hA) {
#pragma unroll
            for (int k = 0; k < 8; ++k)
                ia_[k] = nbr[(ka + k < da) ? (sa + ka + k) : sa];
        }
        if (hB) {
#pragma unroll
            for (int k = 0; k < 8; ++k)
                ib_[k] = nbr[(kb + k < db) ? (sb + kb + k) : sb];
        }
        if (hA) {
#pragma unroll
            for (int k = 0; k < 8; ++k) {
                const float2 v = *reinterpret_cast<const float2*>(x + (size_t)ia_[k] * NF + f);
                const float m = (ka + k < da) ? 1.f : 0.f;
                asx += m * v.x; asy += m * v.y;
                aqx += m * v.x * v.x; aqy += m * v.y * v.y;
            }
        }
        if (hB) {
#pragma unroll
            for (int k = 0; k < 8; ++k) {
                const float2 v = *reinterpret_cast<const float2*>(x + (size_t)ib_[k] * NF + f);
                const float m = (kb + k < db) ? 1.f : 0.f;
                bsx += m * v.x; bsy += m * v.y;
                bqx += m * v.x * v.x; bqy += m * v.y * v.y;
            }
        }
        ka += 8; kb += 8;
    }

    // ---- batch norm ----
    float xba_x = (xa.x - c0.x) * c0.y, xba_y = (xa.y - d0.x) * d0.y;
    float xbb_x = (xb.x - c0.x) * c0.y, xbb_y = (xb.y - d0.x) * d0.y;

    // ---- graph norm ----
    const int ga = gid[i0], gb = gid[i1];
    const float2 mga = *reinterpret_cast<const float2*>(gmu + (size_t)ga * NF + f);
    const float2 rga = *reinterpret_cast<const float2*>(grs + (size_t)ga * NF + f);
    const float2 mgb = *reinterpret_cast<const float2*>(gmu + (size_t)gb * NF + f);
    const float2 rgb = *reinterpret_cast<const float2*>(grs + (size_t)gb * NF + f);
    float xga_x = (xa.x - mga.x) * rga.x, xga_y = (xa.y - mga.y) * rga.y;
    float xgb_x = (xb.x - mgb.x) * rgb.x, xgb_y = (xb.y - mgb.y) * rgb.y;

    // ---- node norm (two wave reductions per node) ----
    float sA = xa.x + xa.y, sB = xb.x + xb.y;
#pragma unroll
    for (int d = 1; d < 64; d <<= 1) { sA += __shfl_xor(sA, d, 64); sB += __shfl_xor(sB, d, 64); }
    const float mnA = sA * (1.0f / NF), mnB = sB * (1.0f / NF);
    float dax = xa.x - mnA, day = xa.y - mnA, dbx = xb.x - mnB, dby = xb.y - mnB;
    float qA = dax * dax + day * day, qB = dbx * dbx + dby * dby;
#pragma unroll
    for (int d = 1; d < 64; d <<= 1) { qA += __shfl_xor(qA, d, 64); qB += __shfl_xor(qB, d, 64); }
    const float rvnA = rsqrtf(qA * (1.0f / NF) + EPSF);
    const float rvnB = rsqrtf(qB * (1.0f / NF) + EPSF);
    float xna_x = dax * rvnA, xna_y = day * rvnA;
    float xnb_x = dbx * rvnB, xnb_y = dby * rvnB;

    // ---- adjacency finish ----
    float dga = (float)da; if (dga < 1.f) dga = 1.f;
    float dgb = (float)db; if (dgb < 1.f) dgb = 1.f;
    float rda = 1.0f / dga, rdb = 1.0f / dgb;
    float maa = asx * rda, mab = asy * rda;
    float vaa = aqx * rda - maa * maa; if (vaa < 0.f) vaa = 0.f;
    float vab = aqy * rda - mab * mab; if (vab < 0.f) vab = 0.f;
    float xaa_x = (xa.x - maa) * rsqrtf(vaa + EPSF);
    float xaa_y = (xa.y - mab) * rsqrtf(vab + EPSF);
    float mba = bsx * rdb, mbb = bsy * rdb;
    float vba = bqx * rdb - mba * mba; if (vba < 0.f) vba = 0.f;
    float vbb = bqy * rdb - mbb * mbb; if (vbb < 0.f) vbb = 0.f;
    float xab_x = (xb.x - mba) * rsqrtf(vba + EPSF);
    float xab_y = (xb.y - mbb) * rsqrtf(vbb + EPSF);

    // ---- combine (softmax(lambda)*gamma pre-folded) ----
    float oa_x = c0.z * xba_x + c0.w * xga_x + c1.x * xaa_x + c1.y * xna_x + c1.z;
    float oa_y = d0.z * xba_y + d0.w * xga_y + d1.x * xaa_y + d1.y * xna_y + d1.z;
    float ob_x = c0.z * xbb_x + c0.w * xgb_x + c1.x * xab_x + c1.y * xnb_x + c1.z;
    float ob_y = d0.z * xbb_y + d0.w * xgb_y + d1.x * xab_y + d1.y * xnb_y + d1.z;
    *reinterpret_cast<float2*>(out + (size_t)i0 * NF + f) = make_float2(oa_x, oa_y);
    *reinterpret_cast<float2*>(out + (size_t)i1 * NF + f) = make_float2(ob_x, ob_y);
}

extern "C" void kernel_launch(void* const* d_in, const int* in_sizes, int n_in,
                              void* d_out, int out_size, void* d_ws, size_t ws_size,
                              hipStream_t stream) {
    const float* x     = (const float*)d_in[0];
    const float* gamma = (const float*)d_in[1];
    const float* beta  = (const float*)d_in[2];
    const float* lb    = (const float*)d_in[3];
    const float* lg    = (const float*)d_in[4];
    const float* la    = (const float*)d_in[5];
    const float* ln    = (const float*)d_in[6];
    const int*   gid   = (const int*)d_in[7];
    const int*   esrc  = (const int*)d_in[8];
    const int*   edst  = (const int*)d_in[9];
    float*       out   = (float*)d_out;

    // ---- workspace layout (4B units); zeroed region first ----
    float* ws    = (float*)d_ws;
    float* bsum  = ws;                              // 128
    float* bsq   = bsum + NF;                       // 128
    float* gsum  = bsq + NF;                        // NG*NF (becomes gmu)
    float* gsq   = gsum + (size_t)NG * NF;          // NG*NF (becomes grs)
    int*   cnt   = (int*)(gsq + (size_t)NG * NF);   // NG
    int*   deg   = cnt + NG;                        // N
    int*   total = deg + N_NODES;                   // 1 (+1 pad)
    // ---- zeroed region ends here ----
    int*   cursor= total + 2;                       // N
    int2*  odeg  = (int2*)(cursor + N_NODES);       // N int2 (8B aligned: offset even)
    int*   nbr   = (int*)(odeg + N_NODES);          // NE
    float* fc    = (float*)(nbr + NE);              // NF*8

    const size_t zero_elems = (size_t)2 * NF + (size_t)2 * NG * NF + NG + N_NODES + 2;
    hipMemsetAsync(d_ws, 0, zero_elems * sizeof(float), stream);

    k1_stats_deg<<<STATS_NB + DEG_NB, 256, 0, stream>>>(
        x, gid, edst, gsum, gsq, cnt, deg);
    k2_alloc_bred<<<ALLOC_NB + BRED_NB, 256, 0, stream>>>(
        deg, odeg, cursor, total, gsum, gsq, bsum, bsq);
    k3_fill_prep<<<DEG_NB + PREP_NB, 256, 0, stream>>>(
        esrc, edst, cursor, nbr, gsum, gsq, cnt, bsum, bsq,
        gamma, beta, lb, lg, la, ln, fc);
    k5_final<<<N_NODES / 8, 256, 0, stream>>>(
        x, gid, gsum, gsq, fc, odeg, nbr, out);
}